// Round 1
// 22.542 us; speedup vs baseline: 1.4397x; 1.4397x over previous
//
#include <hip/hip_runtime.h>
#include <math.h>

#define NF 12
#define NB 4096
#define NR 4096
#define NO 8

typedef float f32x4v __attribute__((ext_vector_type(4)));
typedef short bf16x8 __attribute__((ext_vector_type(8)));
typedef unsigned int uint32x4 __attribute__((ext_vector_type(4)));

// ---- new-path ws layout ----
#define PT2_BYTES (128 * 8 * 512 * 2)      // 1,048,576 : bf16 [kt][j<8][512] fragment-ordered
#define PARAMS_OFF PT2_BYTES               // 48 f32
// ---- r2 fallback ws layout ----
#define PT_ELEMS (112 * 4096)

__device__ __forceinline__ float softplus_f(float v) {
    return fmaxf(v, 0.0f) + log1pf(__expf(-fabsf(v)));
}
__device__ __forceinline__ unsigned short f2bf(float f) {
    unsigned u = __float_as_uint(f);
    u += 0x7FFFu + ((u >> 16) & 1u);
    return (unsigned short)(u >> 16);
}
__device__ __forceinline__ unsigned cvt_pk_bf16(float a, float b) {
    unsigned r;
    asm("v_cvt_pk_bf16_f32 %0, %1, %2" : "=v"(r) : "v"(a), "v"(b));
    return r;
}

// fn value split into hi+lo bf16 (error ~2^-18), 8 k-elems per lane
__device__ __forceinline__ void build_afrag(f32x4v lo0, f32x4v lo1, float hv,
                                            bf16x8& ah, bf16x8& al) {
    float v0 = lo0[0]*hv, v1 = lo0[1]*hv, v2 = lo0[2]*hv, v3 = lo0[3]*hv;
    float v4 = lo1[0]*hv, v5 = lo1[1]*hv, v6 = lo1[2]*hv, v7 = lo1[3]*hv;
    unsigned h0 = cvt_pk_bf16(v0, v1), h1 = cvt_pk_bf16(v2, v3);
    unsigned h2 = cvt_pk_bf16(v4, v5), h3 = cvt_pk_bf16(v6, v7);
    float e0 = v0 - __uint_as_float(h0 << 16), e1 = v1 - __uint_as_float(h0 & 0xFFFF0000u);
    float e2 = v2 - __uint_as_float(h1 << 16), e3 = v3 - __uint_as_float(h1 & 0xFFFF0000u);
    float e4 = v4 - __uint_as_float(h2 << 16), e5 = v5 - __uint_as_float(h2 & 0xFFFF0000u);
    float e6 = v6 - __uint_as_float(h3 << 16), e7 = v7 - __uint_as_float(h3 & 0xFFFF0000u);
    unsigned q0 = cvt_pk_bf16(e0, e1), q1 = cvt_pk_bf16(e2, e3);
    unsigned q2 = cvt_pk_bf16(e4, e5), q3 = cvt_pk_bf16(e6, e7);
    union { uint32x4 u; bf16x8 v; } A, B;
    A.u = (uint32x4){h0, h1, h2, h3};
    B.u = (uint32x4){q0, q1, q2, q3};
    ah = A.v; al = B.v;
}

// ---------------- prep: PT2 fragment-ordered + membership params + out zero ----------------
__global__ __launch_bounds__(512) void anfis_prep2(
    const float* __restrict__ cp, const float* __restrict__ cr,
    const float* __restrict__ center_base, const float* __restrict__ cdr,
    const float* __restrict__ wr,
    unsigned short* __restrict__ PT2, float* __restrict__ params,
    float* __restrict__ out_zero)
{
    __shared__ float s_cp[32 * 97];
    __shared__ float s_cr[32 * 8];
    const int kt = blockIdx.x;       // 0..127
    const int tid = threadIdx.x;

    // zero the output accumulator (stream-ordered before anfis_main4's atomics)
    if (kt < 64) out_zero[(size_t)kt * 512 + tid] = 0.0f;   // 64*512 == 4096*8

    {   // coalesced stage of this kt's 32 rules
        const float4* cp4 = (const float4*)(cp + (size_t)kt * 32 * 96);
        for (int i = tid; i < 768; i += 512) {
            float4 v = cp4[i];
            int r = i / 24, c4 = i - r * 24;
            float* d = &s_cp[r * 97 + c4 * 4];
            d[0] = v.x; d[1] = v.y; d[2] = v.z; d[3] = v.w;
        }
        if (tid < 64) {
            float4 v = ((const float4*)(cr + (size_t)kt * 32 * 8))[tid];
            float* d = &s_cr[tid * 4];
            d[0] = v.x; d[1] = v.y; d[2] = v.z; d[3] = v.w;
        }
    }
    __syncthreads();

    const int g = tid >> 7, col = (tid >> 3) & 15, e = tid & 7;
    const int rr = g * 8 + e;
    #pragma unroll
    for (int j = 0; j < 8; ++j) {
        int n = j * 16 + col;
        float v = 0.f;
        if (n < 96) v = s_cp[rr * 97 + n];
        else if (n < 104) v = s_cr[rr * 8 + (n - 96)];
        PT2[(size_t)(kt * 8 + j) * 512 + tid] = f2bf(v);
    }

    if (kt == 0 && tid < NF) {
        float c0 = center_base[tid];
        float gap = softplus_f(cdr[tid]) + 1e-3f;
        float w0 = softplus_f(wr[tid * 2 + 0]) + 1e-3f;
        float w1 = softplus_f(wr[tid * 2 + 1]) + 1e-3f;
        params[tid * 4 + 0] = c0;
        params[tid * 4 + 1] = c0 + gap;
        params[tid * 4 + 2] = -0.5f / (w0 * w0);
        params[tid * 4 + 3] = -0.5f / (w1 * w1);
    }
}

// ---------------- main: BM=64, 8 waves = 4 row-groups x 2 col-groups ----------------
// Fused epilogue: acc -> LDS (overlaying dead s_B) -> x-weighted reduce -> atomicAdd out.
__global__ __launch_bounds__(512, 4) void anfis_main4(
    const float* __restrict__ x,
    const unsigned short* __restrict__ PT2,
    const float* __restrict__ params,
    float* __restrict__ out,
    const int ktPer)                      // k-tiles (of 32 rules) per block
{
    __shared__ float s_mf[64 * 24];       // [row][f*2+m]
    __shared__ float s_prod[64 * 8];
    __shared__ float s_rcp[64];
    __shared__ float s_x[64 * 12];        // x rows, for fused epilogue
    __shared__ float s_low[64 * 36];      // [row][32] features 0..4
    __shared__ float s_high[64 * 36];     // [row][<=32] features 5..11 * rcp
    __shared__ __align__(16) unsigned char s_B[2 * 16384];

    const int tid = threadIdx.x;
    const int mt = blockIdx.x & 63;
    const int ks = blockIdx.x >> 6;
    const int b0 = mt * 64;
    const int kt0 = ks * ktPer;
    const int nCh = ktPer >> 1;           // chunks of K=64 (2 kt-tiles)
    const int nHiPer = ktPer >> 3;        // high entries per worker-thread

    // ---- memberships (parallel over 64 rows x 6 feature-pairs) ----
    if (tid < 384) {
        int row = tid / 6, fp = tid - row * 6;
        float pr = 1.f;
        #pragma unroll
        for (int h = 0; h < 2; ++h) {
            int f = fp + h * 6;
            float xv = x[(size_t)(b0 + row) * NF + f];
            s_x[row * 12 + f] = xv;
            float4 pm = *(const float4*)&params[f * 4];
            float d0 = xv - pm.x, d1 = xv - pm.y;
            float m0 = __expf(d0 * d0 * pm.z);
            float m1 = __expf(d1 * d1 * pm.w);
            s_mf[row * 24 + f * 2 + 0] = m0;
            s_mf[row * 24 + f * 2 + 1] = m1;
            pr *= (m0 + m1);
        }
        s_prod[row * 8 + fp] = pr;
    }
    __syncthreads();
    if (tid < 64) {
        float S = 1.f;
        #pragma unroll
        for (int i = 0; i < 6; ++i) S *= s_prod[tid * 8 + i];
        s_rcp[tid] = 1.0f / (S + 1e-8f);
    }
    __syncthreads();

    // ---- low[32] and high[ktPer] tables ----
    {
        int row = tid >> 3, w8 = tid & 7;
        const float* mr = &s_mf[row * 24];
        #pragma unroll
        for (int i = 0; i < 4; ++i) {
            int ee = w8 * 4 + i;
            float p = 1.f;
            #pragma unroll
            for (int f = 0; f < 5; ++f) p *= mr[f * 2 + ((ee >> f) & 1)];
            s_low[row * 36 + ee] = p;
        }
        float rc = s_rcp[row];
        for (int i = 0; i < nHiPer; ++i) {
            int t = w8 * nHiPer + i;
            int ktg = kt0 + t;
            float p = rc;
            #pragma unroll
            for (int ff = 0; ff < 7; ++ff) p *= mr[(5 + ff) * 2 + ((ktg >> ff) & 1)];
            s_high[row * 36 + t] = p;
        }
    }
    __syncthreads();

    // ---- K loop ----
    const int w = tid >> 6, l = tid & 63;
    const int rg = w >> 1, cg = w & 1;
    const int col = l & 15, g = l >> 4;
    const int rowA = rg * 16 + col;

    f32x4v lo0 = *(const f32x4v*)&s_low[rowA * 36 + g * 8];
    f32x4v lo1 = *(const f32x4v*)&s_low[rowA * 36 + g * 8 + 4];
    const float* hptr = &s_high[rowA * 36];

    f32x4v acc[4];
    #pragma unroll
    for (int jj = 0; jj < 4; ++jj) acc[jj] = (f32x4v){0.f, 0.f, 0.f, 0.f};

    const unsigned char* ptBase = (const unsigned char*)PT2;

    #define STAGE(c, buf) do {                                                        \
        const unsigned char* gb = ptBase + ((size_t)(kt0 + 2 * (c)) << 13);           \
        unsigned char* lb = &s_B[(buf) * 16384];                                      \
        __builtin_amdgcn_global_load_lds(                                             \
            (const __attribute__((address_space(1))) void*)(gb + w * 1024 + l * 16),  \
            (__attribute__((address_space(3))) void*)(lb + w * 1024), 16, 0, 0);      \
        __builtin_amdgcn_global_load_lds(                                             \
            (const __attribute__((address_space(1))) void*)(gb + (8 + w) * 1024 + l * 16), \
            (__attribute__((address_space(3))) void*)(lb + (8 + w) * 1024), 16, 0, 0);\
    } while (0)

    STAGE(0, 0);
    __syncthreads();

    for (int c = 0; c < nCh; ++c) {
        const int cur = c & 1;
        if (c + 1 < nCh) STAGE(c + 1, cur ^ 1);
        #pragma unroll
        for (int kt2 = 0; kt2 < 2; ++kt2) {
            const unsigned char* fp8 = &s_B[cur * 16384 + kt2 * 8192 + cg * 4096 + l * 16];
            bf16x8 fr0 = *(const bf16x8*)(fp8);
            bf16x8 fr1 = *(const bf16x8*)(fp8 + 1024);
            bf16x8 fr2 = *(const bf16x8*)(fp8 + 2048);
            bf16x8 fr3 = *(const bf16x8*)(fp8 + 3072);
            float hv = hptr[c * 2 + kt2];
            bf16x8 ah, al;
            build_afrag(lo0, lo1, hv, ah, al);
            acc[0] = __builtin_amdgcn_mfma_f32_16x16x32_bf16(ah, fr0, acc[0], 0, 0, 0);
            acc[0] = __builtin_amdgcn_mfma_f32_16x16x32_bf16(al, fr0, acc[0], 0, 0, 0);
            acc[1] = __builtin_amdgcn_mfma_f32_16x16x32_bf16(ah, fr1, acc[1], 0, 0, 0);
            acc[1] = __builtin_amdgcn_mfma_f32_16x16x32_bf16(al, fr1, acc[1], 0, 0, 0);
            acc[2] = __builtin_amdgcn_mfma_f32_16x16x32_bf16(ah, fr2, acc[2], 0, 0, 0);
            acc[2] = __builtin_amdgcn_mfma_f32_16x16x32_bf16(al, fr2, acc[2], 0, 0, 0);
            acc[3] = __builtin_amdgcn_mfma_f32_16x16x32_bf16(ah, fr3, acc[3], 0, 0, 0);
            acc[3] = __builtin_amdgcn_mfma_f32_16x16x32_bf16(al, fr3, acc[3], 0, 0, 0);
        }
        __syncthreads();
    }
    #undef STAGE

    // ---- fused epilogue ----
    // s_B is dead after the final barrier (all waves' reads done, no outstanding
    // global_load_lds targets it). Overlay acc tile [64 rows][112 cols] stride 116
    // (116*4 mod 128 spreads banks; store pattern is 2-way -> free).
    float* s_acc = (float*)s_B;           // 64*116*4 = 29,696 B <= 32,768 B
    #pragma unroll
    for (int jj = 0; jj < 4; ++jj) {
        if (cg == 0 || jj < 3) {
            int j = cg * 4 + jj;
            #pragma unroll
            for (int q = 0; q < 4; ++q)
                s_acc[(rg * 16 + g * 4 + q) * 116 + j * 16 + col] = acc[jj][q];
        }
    }
    __syncthreads();
    {
        const int row = tid >> 3, o = tid & 7;
        const float* ar = &s_acc[row * 116];
        float t = ar[96 + o];
        #pragma unroll
        for (int f = 0; f < NF; ++f) t = fmaf(s_x[row * 12 + f], ar[f * 8 + o], t);
        atomicAdd(&out[(size_t)(b0 + row) * NO + o], t);
    }
}

// ================= round-2 fallback path (proven; used only if ws too small) =================
__global__ __launch_bounds__(256) void anfis_prep(
    const float* __restrict__ cp, const float* __restrict__ cr,
    unsigned short* __restrict__ PT)
{
    const int n = blockIdx.x;
    const int t = threadIdx.x;
    if (n < 96) {
        #pragma unroll
        for (int i = 0; i < 16; ++i) { int r = i * 256 + t; PT[n * 4096 + r] = f2bf(cp[r * 96 + n]); }
    } else if (n < 104) {
        const int o = n - 96;
        #pragma unroll
        for (int i = 0; i < 16; ++i) { int r = i * 256 + t; PT[n * 4096 + r] = f2bf(cr[r * 8 + o]); }
    } else {
        #pragma unroll
        for (int i = 0; i < 16; ++i) PT[n * 4096 + i * 256 + t] = 0;
    }
}

__global__ __launch_bounds__(512) void anfis_mfma(
    const float* __restrict__ x,
    const float* __restrict__ center_base,
    const float* __restrict__ center_delta_raw,
    const float* __restrict__ width_raw,
    const unsigned short* __restrict__ PT,
    float* __restrict__ out)
{
    __shared__ float s_mem[16 * 26];
    __shared__ float s_low[16 * 36];
    __shared__ float s_high[16 * 132];
    __shared__ float s_red[8 * 16 * 113];

    const int tid = threadIdx.x;
    const int b0 = blockIdx.x * 16;

    if (tid < 16) {
        const int b = b0 + tid;
        float S = 1.0f;
        #pragma unroll
        for (int f = 0; f < NF; ++f) {
            float cb  = center_base[f];
            float gap = softplus_f(center_delta_raw[f]) + 1e-3f;
            float c0 = cb, c1 = cb + gap;
            float w0 = softplus_f(width_raw[f * 2 + 0]) + 1e-3f;
            float w1 = softplus_f(width_raw[f * 2 + 1]) + 1e-3f;
            float xv = x[b * NF + f];
            float d0 = xv - c0, d1 = xv - c1;
            float m0 = __expf(-d0 * d0 / (2.0f * w0 * w0));
            float m1 = __expf(-d1 * d1 / (2.0f * w1 * w1));
            s_mem[tid * 26 + f * 2 + 0] = m0;
            s_mem[tid * 26 + f * 2 + 1] = m1;
            S *= (m0 + m1);
        }
        s_mem[tid * 26 + 24] = 1.0f / (S + 1e-8f);
    }
    __syncthreads();
    if (tid < 256) {
        const int row = tid >> 4, w16 = tid & 15;
        const float* mrow = &s_mem[row * 26];
        #pragma unroll
        for (int e = 2 * w16; e <= 2 * w16 + 1; ++e) {
            float p = 1.0f;
            #pragma unroll
            for (int f = 0; f < 5; ++f) p *= mrow[f * 2 + ((e >> f) & 1)];
            s_low[row * 36 + e] = p;
        }
        float rcp = mrow[24];
        #pragma unroll
        for (int i = 0; i < 8; ++i) {
            int e = w16 + 16 * i;
            float p = rcp;
            #pragma unroll
            for (int ff = 0; ff < 7; ++ff) p *= mrow[(5 + ff) * 2 + ((e >> ff) & 1)];
            s_high[row * 132 + e] = p;
        }
    }
    __syncthreads();

    const int w = tid >> 6;
    const int l = tid & 63;
    const int col = l & 15;
    const int g   = l >> 4;

    f32x4v lo0 = *(const f32x4v*)&s_low[col * 36 + g * 8];
    f32x4v lo1 = *(const f32x4v*)&s_low[col * 36 + g * 8 + 4];
    f32x4v hq0 = *(const f32x4v*)&s_high[col * 132 + w * 16 + 0];
    f32x4v hq1 = *(const f32x4v*)&s_high[col * 132 + w * 16 + 4];
    f32x4v hq2 = *(const f32x4v*)&s_high[col * 132 + w * 16 + 8];
    f32x4v hq3 = *(const f32x4v*)&s_high[col * 132 + w * 16 + 12];

    const unsigned short* pB = PT + (size_t)col * 4096 + g * 8 + w * 512;

    f32x4v acc[7];
    #pragma unroll
    for (int j = 0; j < 7; ++j) acc[j] = (f32x4v){0.f, 0.f, 0.f, 0.f};

    bf16x8 bf[2][7];
    #pragma unroll
    for (int j = 0; j < 7; ++j) bf[0][j] = *(const bf16x8*)(pB + j * 65536 + 0 * 32);
    #pragma unroll
    for (int j = 0; j < 7; ++j) bf[1][j] = *(const bf16x8*)(pB + j * 65536 + 1 * 32);

    #pragma unroll
    for (int s = 0; s < 16; ++s) {
        const float hv = (s < 4) ? hq0[s & 3] : (s < 8) ? hq1[s & 3]
                        : (s < 12) ? hq2[s & 3] : hq3[s & 3];
        bf16x8 ah, al;
        #pragma unroll
        for (int e = 0; e < 8; ++e) {
            float v = ((e < 4) ? lo0[e & 3] : lo1[e & 3]) * hv;
            unsigned short h = f2bf(v);
            float vh = __uint_as_float(((unsigned)h) << 16);
            ah[e] = (short)h;
            al[e] = (short)f2bf(v - vh);
        }
        #pragma unroll
        for (int j = 0; j < 7; ++j) {
            acc[j] = __builtin_amdgcn_mfma_f32_16x16x32_bf16(ah, bf[s & 1][j], acc[j], 0, 0, 0);
            acc[j] = __builtin_amdgcn_mfma_f32_16x16x32_bf16(al, bf[s & 1][j], acc[j], 0, 0, 0);
        }
        if (s + 2 < 16) {
            #pragma unroll
            for (int j = 0; j < 7; ++j)
                bf[s & 1][j] = *(const bf16x8*)(pB + j * 65536 + (s + 2) * 32);
        }
    }

    #pragma unroll
    for (int j = 0; j < 7; ++j)
        #pragma unroll
        for (int q = 0; q < 4; ++q)
            s_red[(w * 16 + g * 4 + q) * 113 + j * 16 + col] = acc[j][q];
    __syncthreads();

    if (tid < 128) {
        const int row = tid >> 3, o = tid & 7;
        float xr[NF];
        #pragma unroll
        for (int f = 0; f < NF; ++f) xr[f] = x[(b0 + row) * NF + f];
        float outv = 0.0f;
        #pragma unroll
        for (int ww = 0; ww < 8; ++ww) {
            const float* ar = &s_red[(ww * 16 + row) * 113];
            float t2 = ar[96 + o];
            #pragma unroll
            for (int f = 0; f < NF; ++f) t2 = fmaf(xr[f], ar[f * 8 + o], t2);
            outv += t2;
        }
        out[(b0 + row) * NO + o] = outv;
    }
}

extern "C" void kernel_launch(void* const* d_in, const int* in_sizes, int n_in,
                              void* d_out, int out_size, void* d_ws, size_t ws_size,
                              hipStream_t stream) {
    const float* x   = (const float*)d_in[0];
    const float* cb  = (const float*)d_in[1];
    const float* cdr = (const float*)d_in[2];
    const float* wr  = (const float*)d_in[3];
    const float* cp  = (const float*)d_in[4];
    const float* cr  = (const float*)d_in[5];
    float* out = (float*)d_out;

    const size_t need_new = (size_t)PARAMS_OFF + 2048;

    if (ws_size >= need_new) {
        const int KS = 8;
        const int ktPer = 128 / KS;
        unsigned short* PT2 = (unsigned short*)d_ws;
        float* params = (float*)((char*)d_ws + PARAMS_OFF);
        anfis_prep2<<<128, 512, 0, stream>>>(cp, cr, cb, cdr, wr, PT2, params, out);
        anfis_main4<<<64 * KS, 512, 0, stream>>>(x, PT2, params, out, ktPer);
    } else if (ws_size >= (size_t)PT_ELEMS * sizeof(unsigned short)) {
        unsigned short* PT = (unsigned short*)d_ws;
        anfis_prep<<<112, 256, 0, stream>>>(cp, cr, PT);
        anfis_mfma<<<NB / 16, 512, 0, stream>>>(x, cb, cdr, wr, PT, out);
    }
}